// Round 7
// baseline (364.802 us; speedup 1.0000x reference)
//
#include <hip/hip_runtime.h>

// ---------------------------------------------------------------------------
// r[b,v] = sum_c (feats[b,c,v] - m[c,v]) / s[c,v] * weights[v,c] + bias[v]
// feats per scale k: GEMM  fmap_k (B*Ck x K=n^2)  @  prf_k^T (K x V)
// Fused epilogue: feats tile * w'[c,v]=weights[v,c]/s[c,v], c-reduced,
// atomicAdd into out (pre-initialized with off[v] = bias - sum m*w').
//
// R6 structure: BM=64 x BN=512 blocks (8 waves) -> each fp32 A element
// crosses L3->L2 exactly ONCE (no N-group duplication). A reg-prefetched
// 2 steps deep into a double-buffered 8KB swizzled LDS tile (1 barrier per
// step); B read straight to registers from fragment-ordered bf16 ws tiles
// (L2-resident). Longest blocks dispatch first; no split-K.
// ---------------------------------------------------------------------------

typedef float f32x4 __attribute__((ext_vector_type(4)));
typedef __bf16 bf16x4 __attribute__((ext_vector_type(4)));
typedef __bf16 bf16x8 __attribute__((ext_vector_type(8)));

#define BM 64
#define BK 64
#define V_DIM 512
#define C_TOT 960
#define B_DIM 128

#define NBLK_TOT 1920            // 128 + 256 + 512 + 1024  (= 8*240)
#define NTILE_B 67               // 49 + 13 + 4 + 1 B-step-tiles
#define TILE_BE 32768            // 512*64 bf16 elems per B tile

#define PREP_BT (NTILE_B * 4)    // 268
#define PREP_WP 1920
#define PREP_OFF 512
#define PREP_BLKS (PREP_BT + PREP_WP + PREP_OFF)

// workspace layout (bytes)
#define WP_BYTES 1966080L                     // 960*512*4
#define BT_BYTES ((long)NTILE_B * TILE_BE * 2) // 4,390,912
#define WS_NEED  (WP_BYTES + BT_BYTES)

// T2 XOR-swizzle inside a [64][64] bf16 tile (16B-chunk granularity)
static __device__ __forceinline__ int swz_idx(int row, int k) {
  return row * 64 + (((k >> 3) ^ (row & 7)) << 3) + (k & 7);
}

template <bool BWS>
__global__ __launch_bounds__(512, 1)
void mega_gemm(const float* __restrict__ f0, const float* __restrict__ f1,
               const float* __restrict__ f2, const float* __restrict__ f3,
               const float* __restrict__ p0, const float* __restrict__ p1,
               const float* __restrict__ p2, const float* __restrict__ p3,
               const __bf16* __restrict__ bws,      // fragment-ordered B tiles
               const float* __restrict__ weights,   // [V, C_TOT]
               const float* __restrict__ fs,        // [C_TOT, V]
               const float* __restrict__ wp,        // [C_TOT, V] or null
               float* __restrict__ out)             // [B, V]
{
  __shared__ __bf16 lds[2 * BM * BK];   // 16 KB: double-buffered A tile

  const int tid  = threadIdx.x;
  const int lane = tid & 63;
  const int wid  = tid >> 6;            // 0..7 : wave's 64-wide V slice

  // bijective XCD-chunked swizzle (1920 = 8*240): consecutive vids (same
  // scale, adjacent M) land on the SAME XCD -> shared B tiles stay in L2.
  const int bid = blockIdx.x;
  const int vid = (bid & 7) * (NBLK_TOT / 8) + (bid >> 3);

  // decode scale + M-block (scale0 first: longest blocks start earliest)
  int sc, y;
  if (vid < 128)       { sc = 0; y = vid; }
  else if (vid < 384)  { sc = 1; y = vid - 128; }
  else if (vid < 896)  { sc = 2; y = vid - 384; }
  else                 { sc = 3; y = vid - 896; }

  const int KT[4]  = {3136, 784, 196, 49};
  const int NST[4] = {49, 13, 4, 1};
  const int COF[4] = {0, 64, 192, 448};
  const int TB[4]  = {0, 49, 62, 66};
  const int CKA[4] = {64, 128, 256, 512};

  const float* fmap = sc == 0 ? f0 : sc == 1 ? f1 : sc == 2 ? f2 : f3;
  const float* prf  = sc == 0 ? p0 : sc == 1 ? p1 : sc == 2 ? p2 : p3;
  const int K      = KT[sc];
  const int nsteps = NST[sc];
  const int Ck     = CKA[sc];
  const int Coff   = COF[sc];
  const int tb     = TB[sc];

  const long bm  = (long)y * BM;        // row offset within this scale's M
  const bool K4  = ((K & 3) == 0);

  f32x4 acc[4][4];
#pragma unroll
  for (int i = 0; i < 4; ++i)
#pragma unroll
    for (int j = 0; j < 4; ++j)
      acc[i][j] = f32x4{0.f, 0.f, 0.f, 0.f};

  f32x4 areg[2];

  // issue the 64x64 fp32 A tile of step ks: 2 chunks of 4 floats per thread
  auto issue_a = [&](int ks) {
#pragma unroll
    for (int i = 0; i < 2; ++i) {
      const int  c   = tid + i * 512;       // 0..1023
      const int  row = c >> 4;              // 0..63
      const int  k0  = (c & 15) << 2;
      const long gk  = (long)ks * BK + k0;
      const float* p = fmap + (bm + row) * (long)K + gk;
      f32x4 t = {0.f, 0.f, 0.f, 0.f};
      if (K4) {
        if (gk + 4 <= K) t = *(const f32x4*)p;
      } else {
        if (gk     < K) t[0] = p[0];
        if (gk + 1 < K) t[1] = p[1];
        if (gk + 2 < K) t[2] = p[2];
        if (gk + 3 < K) t[3] = p[3];
      }
      areg[i] = t;
    }
  };
  auto conv_write = [&](__bf16* buf) {
#pragma unroll
    for (int i = 0; i < 2; ++i) {
      const int c   = tid + i * 512;
      const int row = c >> 4;
      const int k0  = (c & 15) << 2;
      const f32x4 t = areg[i];
      bf16x4 h = { (__bf16)t[0], (__bf16)t[1], (__bf16)t[2], (__bf16)t[3] };
      *(bf16x4*)&buf[swz_idx(row, k0)] = h;
    }
  };
  auto load_b = [&](int ks, bf16x8* br) {
    if constexpr (BWS) {
      const __bf16* tbp = bws + (long)(tb + ks) * TILE_BE;
#pragma unroll
      for (int j = 0; j < 4; ++j)
#pragma unroll
        for (int kc = 0; kc < 2; ++kc)
          br[j * 2 + kc] = *(const bf16x8*)(
              tbp + ((((wid * 4 + j) * 2 + kc) << 6) + lane) * 8);
    } else {
      // fallback only (ws too small): direct fp32 gather + convert
#pragma unroll
      for (int j = 0; j < 4; ++j)
#pragma unroll
        for (int kc = 0; kc < 2; ++kc) {
          const int v    = wid * 64 + j * 16 + (lane & 15);
          const int kcol = ks * 64 + kc * 32 + ((lane >> 4) << 3);
          const float* sp = prf + (long)v * K + kcol;
          bf16x8 h;
#pragma unroll
          for (int e = 0; e < 8; ++e)
            h[e] = (__bf16)((kcol + e < K) ? sp[e] : 0.f);
          br[j * 2 + kc] = h;
        }
    }
  };

  // ---- prologue: fill buf0, prefetch A[1]
  issue_a(0);
  conv_write(lds);                      // compiler inserts the vmcnt wait
  if (1 < nsteps) issue_a(1);
  asm volatile("s_waitcnt lgkmcnt(0)" ::: "memory");
  __builtin_amdgcn_sched_barrier(0);
  __builtin_amdgcn_s_barrier();
  __builtin_amdgcn_sched_barrier(0);

  // ---- main loop: 1 barrier/step, A dbuf (depth-2 reg prefetch), B -> regs
  for (int ks = 0; ks < nsteps; ++ks) {
    const int pp = ks & 1;
    const __bf16* bufr = lds + pp * (BM * BK);
    __bf16*       bufw = lds + (pp ^ 1) * (BM * BK);

    bf16x8 breg[8];
    load_b(ks, breg);                   // issued early, consumed in MFMA phase

    if (ks + 1 < nsteps) {
      conv_write(bufw);                 // waits on areg issued a full step ago
      if (ks + 2 < nsteps) issue_a(ks + 2);
    }

    __builtin_amdgcn_s_setprio(1);
#pragma unroll
    for (int kc = 0; kc < 2; ++kc) {
      const int cx = kc * 4 + (lane >> 4);
      bf16x8 af[4];
#pragma unroll
      for (int i = 0; i < 4; ++i) {
        const int r = i * 16 + (lane & 15);
        af[i] = *(const bf16x8*)&bufr[r * 64 + ((cx ^ (r & 7)) << 3)];
      }
#pragma unroll
      for (int i = 0; i < 4; ++i)
#pragma unroll
        for (int j = 0; j < 4; ++j)
          acc[i][j] = __builtin_amdgcn_mfma_f32_16x16x32_bf16(
              af[i], breg[j * 2 + kc], acc[i][j], 0, 0, 0);
    }
    __builtin_amdgcn_s_setprio(0);

    // drain LDS ops only; A prefetch stays in flight across the barrier
    asm volatile("s_waitcnt lgkmcnt(0)" ::: "memory");
    __builtin_amdgcn_sched_barrier(0);
    __builtin_amdgcn_s_barrier();
    __builtin_amdgcn_sched_barrier(0);
  }

  // ---- epilogue: block rows = 64 channels of ONE batch (Ck % 64 == 0).
  // C/D layout: frag row = (lane>>4)*4 + reg, frag col = lane&15   [m89]
  const int bidx  = (int)(bm / Ck);
  const int cbase = (int)(bm % Ck) + Coff;
  const int lrow  = ((lane >> 4) << 2);
  const int lcol  = lane & 15;

#pragma unroll
  for (int j = 0; j < 4; ++j) {
    const int v = wid * 64 + j * 16 + lcol;
    float s = 0.f;
#pragma unroll
    for (int i = 0; i < 4; ++i) {
      const int cg = cbase + i * 16 + lrow;
#pragma unroll
      for (int r = 0; r < 4; ++r) {
        float wfac;
        if (wp)  wfac = wp[(long)(cg + r) * V_DIM + v];
        else     wfac = weights[(long)v * C_TOT + cg + r]
                        / fs[(long)(cg + r) * V_DIM + v];
        s += acc[i][j][r] * wfac;
      }
    }
    s += __shfl_xor(s, 16);
    s += __shfl_xor(s, 32);
    if (lane < 16)
      atomicAdd(&out[(long)bidx * V_DIM + v], s);
  }
}

// ---------------------------------------------------------------------------
// One prep launch: [0,268) B -> fragment-ordered bf16 [512x64] step-tiles;
// [268,2188) w'; [2188,2700) out init with the constant term.
// ---------------------------------------------------------------------------
__global__ void prep_all(const float* __restrict__ p0, const float* __restrict__ p1,
                         const float* __restrict__ p2, const float* __restrict__ p3,
                         const float* __restrict__ weights,
                         const float* __restrict__ bias,
                         const float* __restrict__ fm,
                         const float* __restrict__ fs,
                         float* __restrict__ wp,      // may be null
                         __bf16* __restrict__ bt,     // may be null
                         float* __restrict__ out)
{
  __shared__ float red[4];
  const int blk = blockIdx.x;
  const int tid = threadIdx.x;

  if (blk < PREP_BT) {
    if (!bt) return;
    const int t = blk >> 2;              // tile 0..66
    const int q = blk & 3;               // quarter (8 of 32 frags)
    const float* prf; int K, ks;
    if (t < 49)      { prf = p0; K = 3136; ks = t; }
    else if (t < 62) { prf = p1; K = 784;  ks = t - 49; }
    else if (t < 66) { prf = p2; K = 196;  ks = t - 62; }
    else             { prf = p3; K = 49;   ks = 0; }
    const long base = (long)t * TILE_BE;
#pragma unroll
    for (int i = 0; i < 4; ++i) {
      const int c2 = tid + i * 256;      // 0..1023
      const int nf = q * 8 + (c2 >> 7);  // frag 0..31 (v-group of 16)
      const int kc = (c2 >> 6) & 1;
      const int ln = c2 & 63;
      const int v    = nf * 16 + (ln & 15);
      const int kcol = ks * 64 + kc * 32 + ((ln >> 4) << 3);
      const float* sp = prf + (long)v * K + kcol;
      bf16x8 h;
#pragma unroll
      for (int e = 0; e < 8; ++e)
        h[e] = (__bf16)((kcol + e < K) ? sp[e] : 0.f);
      *(bf16x8*)&bt[base + (long)(((nf * 2 + kc) << 6) + ln) * 8] = h;
    }
  } else if (blk < PREP_BT + PREP_WP) {
    if (!wp) return;
    const int idx = (blk - PREP_BT) * 256 + tid;   // exactly 960*512
    const int c = idx >> 9;
    const int v = idx & (V_DIM - 1);
    wp[idx] = weights[(long)v * C_TOT + c] / fs[idx];
  } else {
    const int v = blk - (PREP_BT + PREP_WP);       // 0..511
    float s = 0.f;
    for (int c = tid; c < C_TOT; c += 256) {
      const long i = (long)c * V_DIM + v;
      s += fm[i] * weights[(long)v * C_TOT + c] / fs[i];
    }
#pragma unroll
    for (int o = 32; o; o >>= 1) s += __shfl_down(s, o);
    if ((tid & 63) == 0) red[tid >> 6] = s;
    __syncthreads();
    if (tid < B_DIM) {
      const float off = bias[v] - (red[0] + red[1] + red[2] + red[3]);
      out[(long)tid * V_DIM + v] = off;
    }
  }
}

extern "C" void kernel_launch(void* const* d_in, const int* in_sizes, int n_in,
                              void* d_out, int out_size, void* d_ws, size_t ws_size,
                              hipStream_t stream)
{
  const float* fmap0   = (const float*)d_in[0];
  const float* prf0    = (const float*)d_in[1];
  const float* fmap1   = (const float*)d_in[2];
  const float* prf1    = (const float*)d_in[3];
  const float* fmap2   = (const float*)d_in[4];
  const float* prf2    = (const float*)d_in[5];
  const float* fmap3   = (const float*)d_in[6];
  const float* prf3    = (const float*)d_in[7];
  const float* weights = (const float*)d_in[8];
  const float* bias    = (const float*)d_in[9];
  const float* fm      = (const float*)d_in[10];
  const float* fs      = (const float*)d_in[11];
  float* out = (float*)d_out;

  const bool has_wp = ws_size >= (size_t)WP_BYTES;
  const bool has_b  = ws_size >= (size_t)WS_NEED;
  float*  wp = has_wp ? (float*)d_ws : nullptr;
  __bf16* bt = has_b ? (__bf16*)((char*)d_ws + WP_BYTES) : nullptr;

  // 1) single prep launch: B fragment tiles + w' + out init
  prep_all<<<dim3(PREP_BLKS), dim3(256), 0, stream>>>(
      prf0, prf1, prf2, prf3, weights, bias, fm, fs, wp, bt, out);

  // 2) single mega GEMM+readout launch over all 4 scales
  if (has_b) {
    mega_gemm<true><<<dim3(NBLK_TOT), dim3(512), 0, stream>>>(
        fmap0, fmap1, fmap2, fmap3, prf0, prf1, prf2, prf3,
        bt, weights, fs, wp, out);
  } else {
    mega_gemm<false><<<dim3(NBLK_TOT), dim3(512), 0, stream>>>(
        fmap0, fmap1, fmap2, fmap3, prf0, prf1, prf2, prf3,
        nullptr, weights, fs, wp, out);
  }
}

// Round 8
// 157.862 us; speedup vs baseline: 2.3109x; 2.3109x over previous
//
#include <hip/hip_runtime.h>

// ---------------------------------------------------------------------------
// r[b,v] = sum_c (feats[b,c,v] - m[c,v]) / s[c,v] * weights[v,c] + bias[v]
// feats per scale k: GEMM  fmap_k (B*Ck x K=n^2)  @  prf_k^T (K x V)
// Fused epilogue: feats tile * w'[c,v]=weights[v,c]/s[c,v], c-reduced,
// atomicAdd into out (pre-initialized with off[v] = bias - sum m*w').
//
// R7 structure (m97 port): one streaming prep pass converts BOTH fmaps and
// prf to bf16 pre-swizzled [128x64] tile images in workspace; the GEMM hot
// loop is pure  barrier -> global_load_lds x8 -> barrier -> ds_read+MFMA
// (no register round-trip, no convert on the critical path). 128x128 tile,
// BK=64, 4 waves, split-K {4,2,1,1}, 4 blocks/CU.
// ---------------------------------------------------------------------------

typedef float f32x4 __attribute__((ext_vector_type(4)));
typedef __bf16 bf16x4 __attribute__((ext_vector_type(4)));
typedef __bf16 bf16x8 __attribute__((ext_vector_type(8)));

#define BK 64
#define TILE_E 8192              // 128*64 elems per tile image
#define V_DIM 512
#define C_TOT 960
#define B_DIM 128

// A-tile counts per scale: (M/128) * nsteps
#define AT0 3136                 // 64*49
#define AT1 1664                 // 128*13
#define AT2 1024                 // 256*4
#define AT3 512                  // 512*1
#define NAT (AT0 + AT1 + AT2 + AT3)   // 6336
#define NBT 268                  // B tiles: 4*(49+13+4+1)

// prep grid regions
#define PREP_A NAT
#define PREP_B NBT
#define PREP_WP 1920
#define PREP_OFF 512
#define PREP_BLKS (PREP_A + PREP_B + PREP_WP + PREP_OFF)

// workspace layout (bytes): [wp][bt][at]
#define WP_BYTES 1966080L                   // 960*512*4
#define BT_BYTES ((long)NBT * TILE_E * 2)   // 4,390,912
#define AT_BYTES ((long)NAT * TILE_E * 2)   // 103,809,024
#define WS_NEED_B (WP_BYTES + BT_BYTES)
#define WS_NEED_A (WP_BYTES + BT_BYTES + AT_BYTES)

// T2 XOR-swizzle inside a [128][64] bf16 tile (16B-chunk granularity)
static __device__ __forceinline__ int swz_idx(int row, int k) {
  return row * 64 + (((k >> 3) ^ (row & 7)) << 3) + (k & 7);
}

// ---------------------------------------------------------------------------
// GEMM. MODE: 2 = A&B from ws tile images (gl_lds direct)
//             1 = B from ws, A staged inline (fp32->cvt->ds_write)
//             0 = both staged inline
// ---------------------------------------------------------------------------
template <int MODE>
__global__ __launch_bounds__(256, 4)
void gemm_fused(const float* __restrict__ fmap,   // [B*Ck, K] fp32
                const float* __restrict__ prf,    // [V, K] fp32
                const __bf16* __restrict__ at,    // A tile images (MODE==2)
                const __bf16* __restrict__ bt,    // B tile images (MODE>=1)
                const float* __restrict__ weights,
                const float* __restrict__ fs,
                const float* __restrict__ wp,     // [C_TOT, V] or null
                float* __restrict__ out,          // [B, V]
                int Ck, int K, int Coff,
                int nsteps_tot, int kchunks, long atile_base, int btile_base)
{
  __shared__ __bf16 lds_a[TILE_E];   // 16 KB
  __shared__ __bf16 lds_b[TILE_E];   // 16 KB

  const int tid  = threadIdx.x;
  const int lane = tid & 63;
  const int wid  = tid >> 6;
  const int wm   = wid >> 1;
  const int wn   = wid & 1;

  const long bm   = (long)blockIdx.y * 128;
  const int  bn_g = blockIdx.x;        // 0..3
  const int  bn   = bn_g * 128;

  const int z    = blockIdx.z;
  const int qb   = nsteps_tot / kchunks;
  const int rb   = nsteps_tot % kchunks;
  const int s0   = z * qb + (z < rb ? z : rb);
  const int send = s0 + qb + (z < rb ? 1 : 0);

  f32x4 acc[4][4];
#pragma unroll
  for (int i = 0; i < 4; ++i)
#pragma unroll
    for (int j = 0; j < 4; ++j)
      acc[i][j] = f32x4{0.f, 0.f, 0.f, 0.f};

  for (int ks = s0; ks < send; ++ks) {
    __syncthreads();   // previous step's LDS readers done

    if constexpr (MODE == 2) {
      // A: 16 x 1KB linear segments of the pre-swizzled tile image
      const __bf16* asrc = at + (atile_base + (long)blockIdx.y * nsteps_tot + ks) * TILE_E;
#pragma unroll
      for (int i = 0; i < 4; ++i) {
        const int seg = wid * 4 + i;
        __builtin_amdgcn_global_load_lds(
            (const __attribute__((address_space(1))) void*)(asrc + seg * 512 + lane * 8),
            (__attribute__((address_space(3))) void*)(&lds_a[seg * 512]),
            16, 0, 0);
      }
    } else {
      // inline A: fp32 load -> cvt -> swizzled ds_write (fallback)
#pragma unroll
      for (int i = 0; i < 8; ++i) {
        const int  c   = tid + i * 256;        // 2048 chunks of 4
        const int  row = c >> 4;
        const int  k0  = (c & 15) << 2;
        const long gk  = (long)ks * BK + k0;
        const float* p = fmap + (bm + row) * (long)K + gk;
        f32x4 t = {0.f, 0.f, 0.f, 0.f};
        if (gk + 4 <= K) t = *(const f32x4*)p;
        else if (gk < K) {
          t[0] = p[0];
          if (gk + 1 < K) t[1] = p[1];
          if (gk + 2 < K) t[2] = p[2];
          if (gk + 3 < K) t[3] = p[3];
        }
        bf16x4 h = { (__bf16)t[0], (__bf16)t[1], (__bf16)t[2], (__bf16)t[3] };
        *(bf16x4*)&lds_a[swz_idx(row, k0)] = h;
      }
    }

    if constexpr (MODE >= 1) {
      const __bf16* bsrc = bt + (long)(btile_base + bn_g * nsteps_tot + ks) * TILE_E;
#pragma unroll
      for (int i = 0; i < 4; ++i) {
        const int seg = wid * 4 + i;
        __builtin_amdgcn_global_load_lds(
            (const __attribute__((address_space(1))) void*)(bsrc + seg * 512 + lane * 8),
            (__attribute__((address_space(3))) void*)(&lds_b[seg * 512]),
            16, 0, 0);
      }
    } else {
#pragma unroll
      for (int i = 0; i < 8; ++i) {
        const int  c   = tid + i * 256;
        const int  row = c >> 4;
        const int  k0  = (c & 15) << 2;
        const long gk  = (long)ks * BK + k0;
        const float* p = prf + (long)(bn + row) * K + gk;
        f32x4 t = {0.f, 0.f, 0.f, 0.f};
        if (gk + 4 <= K) t = *(const f32x4*)p;
        else if (gk < K) {
          t[0] = p[0];
          if (gk + 1 < K) t[1] = p[1];
          if (gk + 2 < K) t[2] = p[2];
          if (gk + 3 < K) t[3] = p[3];
        }
        bf16x4 h = { (__bf16)t[0], (__bf16)t[1], (__bf16)t[2], (__bf16)t[3] };
        *(bf16x4*)&lds_b[swz_idx(row, k0)] = h;
      }
    }

    __syncthreads();   // drains vmcnt (gl_lds) + lgkmcnt (ds_write)

    // MFMA phase: swizzled conflict-free ds_read_b128 fragments
#pragma unroll
    for (int kc = 0; kc < 2; ++kc) {
      const int cx = kc * 4 + (lane >> 4);
      bf16x8 af[4], bfr[4];
#pragma unroll
      for (int i = 0; i < 4; ++i) {
        const int r = wm * 64 + i * 16 + (lane & 15);
        af[i] = *(const bf16x8*)&lds_a[r * 64 + ((cx ^ (r & 7)) << 3)];
      }
#pragma unroll
      for (int j = 0; j < 4; ++j) {
        const int r = wn * 64 + j * 16 + (lane & 15);
        bfr[j] = *(const bf16x8*)&lds_b[r * 64 + ((cx ^ (r & 7)) << 3)];
      }
#pragma unroll
      for (int i = 0; i < 4; ++i)
#pragma unroll
        for (int j = 0; j < 4; ++j)
          acc[i][j] = __builtin_amdgcn_mfma_f32_16x16x32_bf16(af[i], bfr[j],
                                                              acc[i][j], 0, 0, 0);
    }
  }

  // ---- epilogue: per-wave 64x64 feats sub-tile; all 64 m-rows share one b.
  // C/D layout: frag row = (lane>>4)*4 + reg, frag col = lane&15   [m89]
  const long mbase = bm + wm * 64;
  const int  bidx  = (int)(mbase / Ck);
  const int  cbase = (int)(mbase % Ck) + Coff;
  const int  lrow  = ((lane >> 4) << 2);
  const int  lcol  = lane & 15;

#pragma unroll
  for (int j = 0; j < 4; ++j) {
    const int v = bn + wn * 64 + j * 16 + lcol;
    float s = 0.f;
#pragma unroll
    for (int i = 0; i < 4; ++i) {
      const int cg = cbase + i * 16 + lrow;
#pragma unroll
      for (int r = 0; r < 4; ++r) {
        float wfac;
        if (wp)  wfac = wp[(long)(cg + r) * V_DIM + v];
        else     wfac = weights[(long)v * C_TOT + cg + r]
                        / fs[(long)(cg + r) * V_DIM + v];
        s += acc[i][j][r] * wfac;
      }
    }
    s += __shfl_xor(s, 16);
    s += __shfl_xor(s, 32);
    if (lane < 16)
      atomicAdd(&out[(long)bidx * V_DIM + v], s);
  }
}

// ---------------------------------------------------------------------------
// Convert one fp32 source panel row-block into a bf16 pre-swizzled tile image.
// Image: img[swz_idx(row,k)] = src[rbase+row, ks*64+k], zero-padded past K.
// ---------------------------------------------------------------------------
static __device__ __forceinline__ void conv_tile(const float* __restrict__ src,
                                                 int K, long rbase, int ks,
                                                 __bf16* __restrict__ dst, int tid)
{
#pragma unroll
  for (int it = 0; it < 4; ++it) {
    const int u   = tid + it * 256;          // 1024 units of 8 elems
    const int row = u >> 3;
    const int q8  = u & 7;                   // swizzled 16B-chunk index
    const int k   = ((q8 ^ (row & 7)) << 3); // source k of this chunk
    const long gk = (long)ks * BK + k;
    const float* sp = src + (rbase + row) * (long)K + gk;
    bf16x8 h;
    if (gk + 8 <= K) {
      const f32x4 a = *(const f32x4*)sp;
      const f32x4 b = *(const f32x4*)(sp + 4);
      h[0]=(__bf16)a[0]; h[1]=(__bf16)a[1]; h[2]=(__bf16)a[2]; h[3]=(__bf16)a[3];
      h[4]=(__bf16)b[0]; h[5]=(__bf16)b[1]; h[6]=(__bf16)b[2]; h[7]=(__bf16)b[3];
    } else {
#pragma unroll
      for (int e = 0; e < 8; ++e)
        h[e] = (__bf16)((gk + e < K) ? sp[e] : 0.f);
    }
    *(bf16x8*)&dst[(long)row * 64 + q8 * 8] = h;
  }
}

// ---------------------------------------------------------------------------
// One prep launch: [0,6336) A tile images; [6336,6604) B tile images;
// then w' ; then out init with the constant term.
// ---------------------------------------------------------------------------
__global__ void prep_all(const float* __restrict__ f0, const float* __restrict__ f1,
                         const float* __restrict__ f2, const float* __restrict__ f3,
                         const float* __restrict__ p0, const float* __restrict__ p1,
                         const float* __restrict__ p2, const float* __restrict__ p3,
                         const float* __restrict__ weights,
                         const float* __restrict__ bias,
                         const float* __restrict__ fm,
                         const float* __restrict__ fs,
                         float* __restrict__ wp,      // may be null
                         __bf16* __restrict__ bt,     // may be null
                         __bf16* __restrict__ at,     // may be null
                         float* __restrict__ out)
{
  __shared__ float red[4];
  const int blk = blockIdx.x;
  const int tid = threadIdx.x;

  if (blk < PREP_A) {
    if (!at) return;
    int t = blk; const float* src; int K, y, ks;
    if (t < AT0)             { src = f0; K = 3136; y = t / 49; ks = t % 49; }
    else if (t < AT0 + AT1)  { t -= AT0; src = f1; K = 784; y = t / 13; ks = t % 13; }
    else if (t < AT0+AT1+AT2){ t -= AT0 + AT1; src = f2; K = 196; y = t / 4; ks = t % 4; }
    else                     { t -= AT0 + AT1 + AT2; src = f3; K = 49; y = t; ks = 0; }
    conv_tile(src, K, (long)y * 128, ks, at + (long)blk * TILE_E, tid);
  } else if (blk < PREP_A + PREP_B) {
    if (!bt) return;
    int t = blk - PREP_A; const float* src; int K, g, ks;
    if (t < 196)      { src = p0; K = 3136; g = t / 49; ks = t % 49; }
    else if (t < 248) { t -= 196; src = p1; K = 784; g = t / 13; ks = t % 13; }
    else if (t < 264) { t -= 248; src = p2; K = 196; g = t / 4;  ks = t % 4; }
    else              { t -= 264; src = p3; K = 49;  g = t;      ks = 0; }
    conv_tile(src, K, (long)g * 128, ks, bt + (long)(blk - PREP_A) * TILE_E, tid);
  } else if (blk < PREP_A + PREP_B + PREP_WP) {
    if (!wp) return;
    const int idx = (blk - PREP_A - PREP_B) * 256 + tid;   // exactly 960*512
    const int c = idx >> 9;
    const int v = idx & (V_DIM - 1);
    wp[idx] = weights[(long)v * C_TOT + c] / fs[idx];
  } else {
    const int v = blk - (PREP_A + PREP_B + PREP_WP);       // 0..511
    float s = 0.f;
    for (int c = tid; c < C_TOT; c += 256) {
      const long i = (long)c * V_DIM + v;
      s += fm[i] * weights[(long)v * C_TOT + c] / fs[i];
    }
#pragma unroll
    for (int o = 32; o; o >>= 1) s += __shfl_down(s, o);
    if ((tid & 63) == 0) red[tid >> 6] = s;
    __syncthreads();
    if (tid < B_DIM) {
      const float off = bias[v] - (red[0] + red[1] + red[2] + red[3]);
      out[(long)tid * V_DIM + v] = off;
    }
  }
}

extern "C" void kernel_launch(void* const* d_in, const int* in_sizes, int n_in,
                              void* d_out, int out_size, void* d_ws, size_t ws_size,
                              hipStream_t stream)
{
  const float* fmap0   = (const float*)d_in[0];
  const float* prf0    = (const float*)d_in[1];
  const float* fmap1   = (const float*)d_in[2];
  const float* prf1    = (const float*)d_in[3];
  const float* fmap2   = (const float*)d_in[4];
  const float* prf2    = (const float*)d_in[5];
  const float* fmap3   = (const float*)d_in[6];
  const float* prf3    = (const float*)d_in[7];
  const float* weights = (const float*)d_in[8];
  const float* bias    = (const float*)d_in[9];
  const float* fm      = (const float*)d_in[10];
  const float* fs      = (const float*)d_in[11];
  float* out = (float*)d_out;

  const bool has_wp = ws_size >= (size_t)WP_BYTES;
  const bool has_b  = ws_size >= (size_t)WS_NEED_B;
  const bool has_a  = ws_size >= (size_t)WS_NEED_A;
  float*  wp = has_wp ? (float*)d_ws : nullptr;
  __bf16* bt = has_b ? (__bf16*)((char*)d_ws + WP_BYTES) : nullptr;
  __bf16* at = has_a ? (__bf16*)((char*)d_ws + WP_BYTES + BT_BYTES) : nullptr;

  // 1) single streaming prep: A/B bf16 tile images + w' + out init
  prep_all<<<dim3(PREP_BLKS), dim3(256), 0, stream>>>(
      fmap0, fmap1, fmap2, fmap3, prf0, prf1, prf2, prf3,
      weights, bias, fm, fs, wp, bt, at, out);

  // 2) per-scale GEMM+readout, split-K for 4 blocks/CU
  struct Scale {
    const float* fmap; const float* prf;
    int Ck, K, Coff, nsteps, kch; long abase; int bbase;
  };
  const Scale sc[4] = {
    {fmap0, prf0,  64, 3136,   0, 49, 4,                 0L,   0},  // 1024 blocks
    {fmap1, prf1, 128,  784,  64, 13, 2,               AT0,  196},  // 1024 blocks
    {fmap2, prf2, 256,  196, 192,  4, 1,         AT0 + AT1,  248},  // 1024 blocks
    {fmap3, prf3, 512,   49, 448,  1, 1,   AT0 + AT1 + AT2,  264},  // 2048 blocks
  };
  for (int k = 0; k < 4; ++k) {
    const int M = B_DIM * sc[k].Ck;
    dim3 grid(4, M / 128, sc[k].kch);
    if (has_a) {
      gemm_fused<2><<<grid, dim3(256), 0, stream>>>(
          sc[k].fmap, sc[k].prf, at, bt, weights, fs, wp, out,
          sc[k].Ck, sc[k].K, sc[k].Coff, sc[k].nsteps, sc[k].kch,
          sc[k].abase, sc[k].bbase);
    } else if (has_b) {
      gemm_fused<1><<<grid, dim3(256), 0, stream>>>(
          sc[k].fmap, sc[k].prf, nullptr, bt, weights, fs, wp, out,
          sc[k].Ck, sc[k].K, sc[k].Coff, sc[k].nsteps, sc[k].kch,
          0L, sc[k].bbase);
    } else {
      gemm_fused<0><<<grid, dim3(256), 0, stream>>>(
          sc[k].fmap, sc[k].prf, nullptr, nullptr, weights, fs, wp, out,
          sc[k].Ck, sc[k].K, sc[k].Coff, sc[k].nsteps, sc[k].kch,
          0L, 0);
    }
  }
}

// Round 9
// 110.201 us; speedup vs baseline: 3.3104x; 1.4325x over previous
//
#include <hip/hip_runtime.h>

// ---------------------------------------------------------------------------
// r[b,v] = sum_c (feats[b,c,v] - m[c,v]) / s[c,v] * weights[v,c] + bias[v]
// feats per scale k: GEMM  fmap_k (B*Ck x K=n^2)  @  prf_k^T (K x V)
// Fused epilogue: feats tile * w'[c,v]=weights[v,c]/s[c,v], c-reduced,
// atomicAdd into out (pre-initialized with off[v] = bias - sum m*w').
//
// R8 structure: ONE GEMM launch. Main path: A staged as RAW FP32 via
// global_load_lds into a 32KB swizzled LDS tile (inverse-swizzled per-lane
// source addresses), converted to bf16 on the fragment read; B from
// pre-converted bf16 tile images. Tail path (ragged K-steps + scale3):
// R7-proven bf16-image gl_lds, 1 step/block. No A-image round trip.
// ---------------------------------------------------------------------------

typedef float f32x4 __attribute__((ext_vector_type(4)));
typedef f32x4 __attribute__((aligned(4))) f32x4u;
typedef __bf16 bf16x4 __attribute__((ext_vector_type(4)));
typedef __bf16 bf16x8 __attribute__((ext_vector_type(8)));

#define TILE_E 8192              // 128x64 elems per tile
#define V_DIM 512
#define C_TOT 960
#define B_DIM 128

#define NBT 268                  // B tiles (all steps, all scales)
#define NRA 896                  // ragged A tiles: 128(s1) + 256(s2) + 512(s3)
#define PREP_WP 1920
#define PREP_OFF 512
#define PREP_BLKS (NBT + NRA + PREP_WP + PREP_OFF)

#define GEMM_BLKS 6144           // 1024(s0) + 512(s1) + 1024(s2) + 3584(tail) = 8*768

// workspace layout (bytes): [wp][bt][ra]
#define WP_BYTES 1966080L
#define BT_BYTES ((long)NBT * TILE_E * 2)   // 4,390,912
#define RA_BYTES ((long)NRA * TILE_E * 2)   // 14,680,064
#define WS_NEED  (WP_BYTES + BT_BYTES + RA_BYTES)

// T2 XOR-swizzle, 16B granularity, inside a [128][64]-elem tile
static __device__ __forceinline__ int swz_idx(int row, int k) {   // bf16 elems
  return row * 64 + (((k >> 3) ^ (row & 7)) << 3) + (k & 7);
}

// ---------------------------------------------------------------------------
// Fused GEMM, single launch. Block decode (after XCD interleave):
//   w in [0,1024): s0 full steps (fp32-A), 64y*4x*4z, steps 12/12/12/13
//   w in [1024,1536): s1 full steps 0..11
//   w in [1536,2560): s2 full steps 0..2
//   w in [2560,6144): tail (1 bf16-image step): s1@12, s2@3, s3@0
// ---------------------------------------------------------------------------
__global__ __launch_bounds__(256, 3)
void gemm_all(const float* __restrict__ f0, const float* __restrict__ f1,
              const float* __restrict__ f2,
              const __bf16* __restrict__ bt,   // B tile images
              const __bf16* __restrict__ ra,   // ragged-A tile images
              const float* __restrict__ wp,    // [C_TOT, V]
              float* __restrict__ out)         // [B, V]
{
  __shared__ float  lds_af[TILE_E];   // 32 KB fp32 A (tail reuses as bf16)
  __shared__ __bf16 lds_b[TILE_E];    // 16 KB B

  const int tid  = threadIdx.x;
  const int lane = tid & 63;
  const int wid  = tid >> 6;
  const int wm   = wid >> 1;
  const int wn   = wid & 1;

  // XCD-interleaved, x-quad-preserving decode: each XCD gets every-8th quad
  // of the LPT-ordered (longest-first) work list; 4 N-siblings co-locate.
  const int bid   = blockIdx.x;
  const int sslot = bid >> 3;
  const int xcd   = bid & 7;
  const int w     = (((sslot >> 2) << 3) + xcd) * 4 + (sslot & 3);

  f32x4 acc[4][4];
#pragma unroll
  for (int i = 0; i < 4; ++i)
#pragma unroll
    for (int j = 0; j < 4; ++j)
      acc[i][j] = f32x4{0.f, 0.f, 0.f, 0.f};

  int Ck, Coff, bn_g, bn;
  long bm;

  if (w < 2560) {
    // ======================= MAIN: fp32-A full steps =======================
    const float* fmap; int K, nst, bbase, y, s0k, sendk;
    if (w < 1024) {
      fmap = f0; K = 3136; nst = 49; bbase = 0; Ck = 64; Coff = 0;
      bn_g = w & 3; y = (w >> 2) & 63;
      const int z = w >> 8; s0k = z * 12; sendk = (z == 3) ? 49 : s0k + 12;
    } else if (w < 1536) {
      const int l = w - 1024;
      fmap = f1; K = 784; nst = 13; bbase = 196; Ck = 128; Coff = 64;
      bn_g = l & 3; y = l >> 2; s0k = 0; sendk = 12;
    } else {
      const int l = w - 1536;
      fmap = f2; K = 196; nst = 4; bbase = 248; Ck = 256; Coff = 192;
      bn_g = l & 3; y = l >> 2; s0k = 0; sendk = 3;
    }
    bm = (long)y * 128; bn = bn_g * 128;

    for (int ks = s0k; ks < sendk; ++ks) {
      __syncthreads();   // previous step's LDS readers done

      // stage A: raw fp32, inverse-swizzled per-lane source, linear LDS dest
      const float* ab = fmap + bm * (long)K + (long)ks * 64;
#pragma unroll
      for (int i = 0; i < 8; ++i) {
        const int seg = wid * 8 + i;
        const int cc  = seg * 64 + lane;       // dest 16B-chunk 0..2047
        const int row = cc >> 4;
        const int q4  = (cc & 15) ^ (row & 7); // source 4-float chunk
        __builtin_amdgcn_global_load_lds(
            (const __attribute__((address_space(1))) void*)(ab + (long)row * K + q4 * 4),
            (__attribute__((address_space(3))) void*)(&lds_af[seg * 256]),
            16, 0, 0);
      }
      // stage B: pre-swizzled bf16 image, linear copy
      const __bf16* bsrc = bt + (long)(bbase + bn_g * nst + ks) * TILE_E;
#pragma unroll
      for (int i = 0; i < 4; ++i) {
        const int seg = wid * 4 + i;
        __builtin_amdgcn_global_load_lds(
            (const __attribute__((address_space(1))) void*)(bsrc + seg * 512 + lane * 8),
            (__attribute__((address_space(3))) void*)(&lds_b[seg * 512]),
            16, 0, 0);
      }
      __syncthreads();   // drains gl_lds (vmcnt) + ds writes

      // fragments: A = 2x ds_read_b128 fp32 + cast; B = bf16 ds_read_b128
#pragma unroll
      for (int kc = 0; kc < 2; ++kc) {
        const int q4a = kc * 8 + ((lane >> 4) << 1);
        const int cx  = kc * 4 + (lane >> 4);
        bf16x8 af[4], bfr[4];
#pragma unroll
        for (int i = 0; i < 4; ++i) {
          const int r = wm * 64 + i * 16 + (lane & 15);
          const f32x4 fa = *(const f32x4*)&lds_af[r * 64 + ((q4a ^ (r & 7)) << 2)];
          const f32x4 fb = *(const f32x4*)&lds_af[r * 64 + (((q4a + 1) ^ (r & 7)) << 2)];
          af[i] = bf16x8{(__bf16)fa[0], (__bf16)fa[1], (__bf16)fa[2], (__bf16)fa[3],
                         (__bf16)fb[0], (__bf16)fb[1], (__bf16)fb[2], (__bf16)fb[3]};
        }
#pragma unroll
        for (int j = 0; j < 4; ++j) {
          const int r = wn * 64 + j * 16 + (lane & 15);
          bfr[j] = *(const bf16x8*)&lds_b[r * 64 + ((cx ^ (r & 7)) << 3)];
        }
#pragma unroll
        for (int i = 0; i < 4; ++i)
#pragma unroll
          for (int j = 0; j < 4; ++j)
            acc[i][j] = __builtin_amdgcn_mfma_f32_16x16x32_bf16(af[i], bfr[j],
                                                                acc[i][j], 0, 0, 0);
      }
    }
  } else {
    // ================== TAIL: one bf16-image step per block =================
    const int l = w - 2560;
    int y, btile;
    long raidx;
    if (l < 512) {
      y = l >> 2; bn_g = l & 3; raidx = y;          Ck = 128; Coff = 64;
      btile = 196 + bn_g * 13 + 12;
    } else if (l < 1536) {
      const int m = l - 512;
      y = m >> 2; bn_g = m & 3; raidx = 128 + y;    Ck = 256; Coff = 192;
      btile = 248 + bn_g * 4 + 3;
    } else {
      const int m = l - 1536;
      y = m >> 2; bn_g = m & 3; raidx = 384 + y;    Ck = 512; Coff = 448;
      btile = 264 + bn_g;
    }
    bm = (long)y * 128; bn = bn_g * 128;

    __bf16* lds_ab = (__bf16*)lds_af;
    const __bf16* asrc = ra + raidx * TILE_E;
    const __bf16* bsrc = bt + (long)btile * TILE_E;
#pragma unroll
    for (int i = 0; i < 4; ++i) {
      const int seg = wid * 4 + i;
      __builtin_amdgcn_global_load_lds(
          (const __attribute__((address_space(1))) void*)(asrc + seg * 512 + lane * 8),
          (__attribute__((address_space(3))) void*)(&lds_ab[seg * 512]),
          16, 0, 0);
      __builtin_amdgcn_global_load_lds(
          (const __attribute__((address_space(1))) void*)(bsrc + seg * 512 + lane * 8),
          (__attribute__((address_space(3))) void*)(&lds_b[seg * 512]),
          16, 0, 0);
    }
    __syncthreads();

#pragma unroll
    for (int kc = 0; kc < 2; ++kc) {
      const int cx = kc * 4 + (lane >> 4);
      bf16x8 af[4], bfr[4];
#pragma unroll
      for (int i = 0; i < 4; ++i) {
        const int r = wm * 64 + i * 16 + (lane & 15);
        af[i] = *(const bf16x8*)&lds_ab[r * 64 + ((cx ^ (r & 7)) << 3)];
      }
#pragma unroll
      for (int j = 0; j < 4; ++j) {
        const int r = wn * 64 + j * 16 + (lane & 15);
        bfr[j] = *(const bf16x8*)&lds_b[r * 64 + ((cx ^ (r & 7)) << 3)];
      }
#pragma unroll
      for (int i = 0; i < 4; ++i)
#pragma unroll
        for (int j = 0; j < 4; ++j)
          acc[i][j] = __builtin_amdgcn_mfma_f32_16x16x32_bf16(af[i], bfr[j],
                                                              acc[i][j], 0, 0, 0);
    }
  }

  // ---- epilogue: per-wave 64x64 feats sub-tile, c-reduce, atomicAdd.
  // C/D layout: frag row = (lane>>4)*4 + reg, frag col = lane&15   [m89]
  const long mbase = bm + wm * 64;
  const int  bidx  = (int)(mbase / Ck);
  const int  cbase = (int)(mbase % Ck) + Coff;
  const int  lrow  = ((lane >> 4) << 2);
  const int  lcol  = lane & 15;

#pragma unroll
  for (int j = 0; j < 4; ++j) {
    const int v = bn + wn * 64 + j * 16 + lcol;
    float s = 0.f;
#pragma unroll
    for (int i = 0; i < 4; ++i) {
      const int cg = cbase + i * 16 + lrow;
#pragma unroll
      for (int r = 0; r < 4; ++r)
        s += acc[i][j][r] * wp[(long)(cg + r) * V_DIM + v];
    }
    s += __shfl_xor(s, 16);
    s += __shfl_xor(s, 32);
    if (lane < 16)
      atomicAdd(&out[(long)bidx * V_DIM + v], s);
  }
}

// ---------------------------------------------------------------------------
// Convert one fp32 row-block into a bf16 pre-swizzled [128x64] tile image.
// img[swz_idx(row,k)] = src[rbase+row, ks*64+k], zero-padded past K.
// ---------------------------------------------------------------------------
static __device__ __forceinline__ void conv_tile(const float* __restrict__ src,
                                                 int K, long rbase, int ks,
                                                 __bf16* __restrict__ dst, int tid)
{
#pragma unroll
  for (int it = 0; it < 4; ++it) {
    const int u   = tid + it * 256;          // 1024 units of 8 elems
    const int row = u >> 3;
    const int q8  = u & 7;                   // stored 16B-chunk
    const int k   = ((q8 ^ (row & 7)) << 3); // source k
    const long gk = (long)ks * 64 + k;
    const float* sp = src + (rbase + row) * (long)K + gk;
    bf16x8 h;
    if (gk + 8 <= K) {
      const f32x4u a = *(const f32x4u*)sp;
      const f32x4u b = *(const f32x4u*)(sp + 4);
      h[0]=(__bf16)a[0]; h[1]=(__bf16)a[1]; h[2]=(__bf16)a[2]; h[3]=(__bf16)a[3];
      h[4]=(__bf16)b[0]; h[5]=(__bf16)b[1]; h[6]=(__bf16)b[2]; h[7]=(__bf16)b[3];
    } else {
#pragma unroll
      for (int e = 0; e < 8; ++e)
        h[e] = (__bf16)((gk + e < K) ? sp[e] : 0.f);
    }
    *(bf16x8*)&dst[(long)row * 64 + q8 * 8] = h;
  }
}

// ---------------------------------------------------------------------------
// One prep launch: [0,268) B images; [268,1164) ragged-A images;
// then w'; then out init with the constant term.
// ---------------------------------------------------------------------------
__global__ void prep_all(const float* __restrict__ f1, const float* __restrict__ f2,
                         const float* __restrict__ f3,
                         const float* __restrict__ p0, const float* __restrict__ p1,
                         const float* __restrict__ p2, const float* __restrict__ p3,
                         const float* __restrict__ weights,
                         const float* __restrict__ bias,
                         const float* __restrict__ fm,
                         const float* __restrict__ fs,
                         float* __restrict__ wp,      // may be null
                         __bf16* __restrict__ bt,     // may be null
                         __bf16* __restrict__ ra,     // may be null
                         float* __restrict__ out)
{
  __shared__ float red[4];
  const int blk = blockIdx.x;
  const int tid = threadIdx.x;

  if (blk < NBT) {
    if (!bt) return;
    int t = blk; const float* src; int K, g, ks;
    if (t < 196)      { src = p0; K = 3136; g = t / 49; ks = t % 49; }
    else if (t < 248) { t -= 196; src = p1; K = 784; g = t / 13; ks = t % 13; }
    else if (t < 264) { t -= 248; src = p2; K = 196; g = t / 4;  ks = t % 4; }
    else              { t -= 264; src = p3; K = 49;  g = t;      ks = 0; }
    conv_tile(src, K, (long)g * 128, ks, bt + (long)blk * TILE_E, tid);
  } else if (blk < NBT + NRA) {
    if (!ra) return;
    const int t = blk - NBT; const float* src; int K, ks; long rbase;
    if (t < 128)      { src = f1; K = 784; ks = 12; rbase = (long)t * 128; }
    else if (t < 384) { src = f2; K = 196; ks = 3;  rbase = (long)(t - 128) * 128; }
    else              { src = f3; K = 49;  ks = 0;  rbase = (long)(t - 384) * 128; }
    conv_tile(src, K, rbase, ks, ra + (long)t * TILE_E, tid);
  } else if (blk < NBT + NRA + PREP_WP) {
    if (!wp) return;
    const int idx = (blk - NBT - NRA) * 256 + tid;   // exactly 960*512
    const int c = idx >> 9;
    const int v = idx & (V_DIM - 1);
    wp[idx] = weights[(long)v * C_TOT + c] / fs[idx];
  } else {
    const int v = blk - (NBT + NRA + PREP_WP);       // 0..511
    float s = 0.f;
    for (int c = tid; c < C_TOT; c += 256) {
      const long i = (long)c * V_DIM + v;
      s += fm[i] * weights[(long)v * C_TOT + c] / fs[i];
    }
#pragma unroll
    for (int o = 32; o; o >>= 1) s += __shfl_down(s, o);
    if ((tid & 63) == 0) red[tid >> 6] = s;
    __syncthreads();
    if (tid < B_DIM) {
      const float off = bias[v] - (red[0] + red[1] + red[2] + red[3]);
      out[(long)tid * V_DIM + v] = off;
    }
  }
}

// ---------------------------------------------------------------------------
// Fallback GEMM (ws too small): inline fp32 staging of both operands.
// ---------------------------------------------------------------------------
__global__ __launch_bounds__(256, 3)
void gemm_fb(const float* __restrict__ fmap, const float* __restrict__ prf,
             const float* __restrict__ weights, const float* __restrict__ fs,
             const float* __restrict__ wp, float* __restrict__ out,
             int Ck, int K, int Coff, int nsteps, int kchunks)
{
  __shared__ __bf16 lds_a[TILE_E];
  __shared__ __bf16 lds_b[TILE_E];
  const int tid = threadIdx.x, lane = tid & 63, wid = tid >> 6;
  const int wm = wid >> 1, wn = wid & 1;
  const long bm = (long)blockIdx.y * 128;
  const int bn = blockIdx.x * 128;
  const int z = blockIdx.z, qb = nsteps / kchunks, rb = nsteps % kchunks;
  const int s0 = z * qb + (z < rb ? z : rb);
  const int send = s0 + qb + (z < rb ? 1 : 0);

  f32x4 acc[4][4];
#pragma unroll
  for (int i = 0; i < 4; ++i)
#pragma unroll
    for (int j = 0; j < 4; ++j) acc[i][j] = f32x4{0.f, 0.f, 0.f, 0.f};

  for (int ks = s0; ks < send; ++ks) {
    __syncthreads();
#pragma unroll
    for (int i = 0; i < 8; ++i) {
      const int c = tid + i * 256, row = c >> 4, k0 = (c & 15) << 2;
      const long gk = (long)ks * 64 + k0;
      const float* ap = fmap + (bm + row) * (long)K + gk;
      const float* bp = prf + (long)(bn + row) * K + gk;
      float a[4], b[4];
#pragma unroll
      for (int e = 0; e < 4; ++e) {
        a[e] = (gk + e < K) ? ap[e] : 0.f;
        b[e] = (gk + e < K) ? bp[e] : 0.f;
      }
      bf16x4 ha = {(__bf16)a[0], (__bf16)a[1], (__bf16)a[2], (__bf16)a[3]};
      bf16x4 hb = {(__bf16)b[0], (__bf16)b[1], (__bf16)b[2], (__bf16)b[3]};
      *(bf16x4*)&lds_a[swz_idx(row, k0)] = ha;
      *(bf16x4*)&lds_b[swz_idx(row, k0)] = hb;
    }
    __syncthreads();
#pragma unroll
    for (int kc = 0; kc < 2; ++kc) {
      const int cx = kc * 4 + (lane >> 4);
      bf16x8 af[4], bfr[4];
#pragma unroll
      for (int i = 0; i < 4; ++i) {
        const int r = wm * 64 + i * 16 + (lane & 15);
        af[i] = *(const bf16x8*)&lds_a[r * 64 + ((cx ^ (r & 7)) << 3)];
      }
#pragma unroll
      for (int j = 0; j < 4; ++j) {
        const int r = wn * 64 + j * 16 + (lane & 15);
        bfr[j] = *(const bf16x8*)&lds_b[r * 64 + ((cx ^ (r & 7)) << 3)];
      }
#pragma unroll
      for (int i = 0; i < 4; ++i)
#pragma unroll
        for (int j = 0; j < 4; ++j)
          acc[i][j] = __builtin_amdgcn_mfma_f32_16x16x32_bf16(af[i], bfr[j],
                                                              acc[i][j], 0, 0, 0);
    }
  }

  const long mbase = bm + wm * 64;
  const int bidx = (int)(mbase / Ck);
  const int cbase = (int)(mbase % Ck) + Coff;
  const int lrow = ((lane >> 4) << 2), lcol = lane & 15;
#pragma unroll
  for (int j = 0; j < 4; ++j) {
    const int v = bn + wn * 64 + j * 16 + lcol;
    float s = 0.f;
#pragma unroll
    for (int i = 0; i < 4; ++i) {
      const int cg = cbase + i * 16 + lrow;
#pragma unroll
      for (int r = 0; r < 4; ++r) {
        const float wf = wp ? wp[(long)(cg + r) * V_DIM + v]
                            : weights[(long)v * C_TOT + cg + r]
                              / fs[(long)(cg + r) * V_DIM + v];
        s += acc[i][j][r] * wf;
      }
    }
    s += __shfl_xor(s, 16);
    s += __shfl_xor(s, 32);
    if (lane < 16) atomicAdd(&out[(long)bidx * V_DIM + v], s);
  }
}

extern "C" void kernel_launch(void* const* d_in, const int* in_sizes, int n_in,
                              void* d_out, int out_size, void* d_ws, size_t ws_size,
                              hipStream_t stream)
{
  const float* fmap0   = (const float*)d_in[0];
  const float* prf0    = (const float*)d_in[1];
  const float* fmap1   = (const float*)d_in[2];
  const float* prf1    = (const float*)d_in[3];
  const float* fmap2   = (const float*)d_in[4];
  const float* prf2    = (const float*)d_in[5];
  const float* fmap3   = (const float*)d_in[6];
  const float* prf3    = (const float*)d_in[7];
  const float* weights = (const float*)d_in[8];
  const float* bias    = (const float*)d_in[9];
  const float* fm      = (const float*)d_in[10];
  const float* fs      = (const float*)d_in[11];
  float* out = (float*)d_out;

  const bool has_wp = ws_size >= (size_t)WP_BYTES;
  const bool has_ws = ws_size >= (size_t)WS_NEED;
  float*  wp = has_wp ? (float*)d_ws : nullptr;
  __bf16* bt = has_ws ? (__bf16*)((char*)d_ws + WP_BYTES) : nullptr;
  __bf16* ra = has_ws ? (__bf16*)((char*)d_ws + WP_BYTES + BT_BYTES) : nullptr;

  // 1) prep: B images + ragged-A images + w' + out init
  prep_all<<<dim3(PREP_BLKS), dim3(256), 0, stream>>>(
      fmap1, fmap2, fmap3, prf0, prf1, prf2, prf3,
      weights, bias, fm, fs, wp, bt, ra, out);

  // 2) single fused GEMM launch (main fp32-A path + image tail path)
  if (has_ws) {
    gemm_all<<<dim3(GEMM_BLKS), dim3(256), 0, stream>>>(
        fmap0, fmap1, fmap2, bt, ra, wp, out);
  } else {
    struct Scale { const float* fmap; const float* prf; int Ck, K, Coff, nst, kch; };
    const Scale sc[4] = {
      {fmap0, prf0,  64, 3136,   0, 49, 4},
      {fmap1, prf1, 128,  784,  64, 13, 2},
      {fmap2, prf2, 256,  196, 192,  4, 1},
      {fmap3, prf3, 512,   49, 448,  1, 1},
    };
    for (int k = 0; k < 4; ++k) {
      dim3 grid(4, B_DIM * sc[k].Ck / 128, sc[k].kch);
      gemm_fb<<<grid, dim3(256), 0, stream>>>(
          sc[k].fmap, sc[k].prf, weights, fs, wp, out,
          sc[k].Ck, sc[k].K, sc[k].Coff, sc[k].nst, sc[k].kch);
    }
  }
}